// Round 12
// baseline (186.900 us; speedup 1.0000x reference)
//
#include <hip/hip_runtime.h>
#include <hip/hip_bf16.h>

typedef __bf16 bf16;
typedef __attribute__((ext_vector_type(8))) __bf16 bf16x8;
typedef __attribute__((ext_vector_type(4))) float f32x4;

#define DEV __device__ __forceinline__

DEV float fexp2(float x) {
#if __has_builtin(__builtin_amdgcn_exp2f)
  return __builtin_amdgcn_exp2f(x);
#else
  return exp2f(x);
#endif
}

// async global->LDS, 16B per lane; LDS dest = wave-uniform base + lane*16
DEV void gload_lds16(const void* g, void* l) {
  __builtin_amdgcn_global_load_lds(
      (__attribute__((address_space(1))) void*)(g),
      (__attribute__((address_space(3))) void*)(l), 16, 0, 0);
}

template <int N>
DEV void waitvm() { asm volatile("s_waitcnt vmcnt(%0)" ::"n"(N) : "memory"); }
DEV void fence() { asm volatile("" ::: "memory"); }
DEV void bar() { fence(); __builtin_amdgcn_s_barrier(); fence(); }

// ---------------- weight conversion (weights only now) ----------------
// Wq/Wk/Wv [16,1024,64] -> WqkvT [3072][1024] (Wq scaled by 0.125*log2e);
// Wo [1024,1024] -> WoT transposed.
__global__ void k_cvt_w(const float* __restrict__ Wq, const float* __restrict__ Wk,
                        const float* __restrict__ Wv, const float* __restrict__ Wo,
                        bf16* __restrict__ WqkvT, bf16* __restrict__ WoT) {
  const int idx = blockIdx.x * blockDim.x + threadIdx.x;  // 0..4M
  const int which = idx >> 20, r = idx & ((1 << 20) - 1);
  if (which < 3) {
    const float* W = which == 0 ? Wq : which == 1 ? Wk : Wv;
    const int d = r & 1023, n = r >> 10;
    float val = W[((size_t)(n >> 6) << 16) + (size_t)d * 64 + (n & 63)];
    if (which == 0) val *= 0.180336880f;  // 1/sqrt(64) * log2(e)
    WqkvT[((size_t)which << 20) + r] = (bf16)val;
  } else {
    const int kk = r & 1023, n = r >> 10;
    WoT[r] = (bf16)Wo[(size_t)kk * 1024 + n];
  }
}

// ---------------- GEMM building blocks ----------------
// bf16 A-stage (out-proj GEMM): gload_lds, pre-swizzled source (8 chunks/row)
DEV void stageA(const bf16* __restrict__ Am, bf16 (*lds)[64], int k0, int tid) {
  const int wv = tid >> 6;
#pragma unroll
  for (int l = 0; l < 2; ++l) {
    const int row = l * 64 + (tid >> 3);
    const int e = (((tid & 7) ^ (row & 7)) << 3);
    gload_lds16(Am + (size_t)row * 1024 + k0 + e,
                (char*)lds + l * 8192 + wv * 1024);
  }
}
// fp32 A-stage (qkv GEMM, fused cast): 16 chunks/row, XOR over row&15.
// 4 gloads/thread; wave dest = l*8192 + wv*1024 (rows l*32+wv*4 .. +4).
DEV void stageAf(const float* __restrict__ Am, float (*lds)[64], int k0, int tid) {
  const int wv = tid >> 6;
#pragma unroll
  for (int l = 0; l < 4; ++l) {
    const int row = l * 32 + (tid >> 4);
    const int ch = (tid & 15) ^ (row & 15);
    gload_lds16(Am + (size_t)row * 1024 + k0 + ch * 4,
                (char*)lds + l * 8192 + wv * 1024);
  }
}
DEV void stageBh(const bf16* __restrict__ Bt, bf16 (*lds)[64], int h, int k0, int tid) {
  const int wv = tid >> 6;
#pragma unroll
  for (int l = 0; l < 2; ++l) {
    const int row = h * 128 + l * 64 + (tid >> 3);
    const int e = (((tid & 7) ^ (row & 7)) << 3);
    gload_lds16(Bt + (size_t)row * 1024 + k0 + e,
                (char*)lds + h * 16384 + l * 8192 + wv * 1024);
  }
}
DEV bf16x8 ldsfrag(const bf16 (*lds)[64], int row, int kk, int lgrp) {
  const int ch = ((kk << 2) + lgrp) ^ (row & 7);
  return *reinterpret_cast<const bf16x8*>((const char*)&lds[row][0] + (ch << 4));
}
// f32 frag read + cvt: source chunks s0,s0+1 cover k [kk*32+lgrp*8, +8)
DEV bf16x8 ldsfragAf(const float (*lds)[64], int row, int kk, int lgrp) {
  const int s0 = (kk << 3) + (lgrp << 1);
  const f32x4 a = *reinterpret_cast<const f32x4*>(
      (const char*)&lds[row][0] + (((s0) ^ (row & 15)) << 4));
  const f32x4 b = *reinterpret_cast<const f32x4*>(
      (const char*)&lds[row][0] + (((s0 + 1) ^ (row & 15)) << 4));
  bf16x8 o;
  o[0] = (bf16)a[0]; o[1] = (bf16)a[1]; o[2] = (bf16)a[2]; o[3] = (bf16)a[3];
  o[4] = (bf16)b[0]; o[5] = (bf16)b[1]; o[6] = (bf16)b[2]; o[7] = (bf16)b[3];
  return o;
}

// K-loop macro for bf16-A GEMM (out-proj; R7/R8-verified schedule)
#define GEMM_KLOOP(Am, Bt, acc)                                               \
  stageA(Am, AsB[0], 0, tid);                                                 \
  stageBh(Bt, BsB[0], 0, 0, tid);                                             \
  stageBh(Bt, BsB[0], 1, 0, tid);                                             \
  stageBh(Bt, BsB[1], 0, 64, tid);                                            \
  stageBh(Bt, BsB[1], 1, 64, tid);                                            \
  waitvm<4>();                                                                \
  bar();                                                                      \
  int cur = 0;                                                                \
  for (int kt = 0; kt < NT; ++kt) {                                           \
    bf16x8 bfr[4][2], afr[2][2];                                              \
    _Pragma("unroll") for (int n = 0; n < 4; ++n)                             \
        _Pragma("unroll") for (int kk = 0; kk < 2; ++kk)                      \
            bfr[n][kk] = ldsfrag(BsB[cur], wn * 64 + n * 16 + lid, kk, lgrp); \
    _Pragma("unroll") for (int mi = 0; mi < 2; ++mi)                          \
        _Pragma("unroll") for (int kk = 0; kk < 2; ++kk)                      \
            afr[mi][kk] = ldsfrag(AsB[cur], wr * 64 + mi * 16 + lid, kk, lgrp); \
    if (kt + 1 < NT) stageA(Am, AsB[cur ^ 1], (kt + 1) * 64, tid);            \
    bar();                                                                    \
    __builtin_amdgcn_s_setprio(1);                                            \
    _Pragma("unroll") for (int mi = 0; mi < 2; ++mi)                          \
        _Pragma("unroll") for (int n = 0; n < 4; ++n)                         \
            _Pragma("unroll") for (int kk = 0; kk < 2; ++kk)                  \
                acc[mi][n] = __builtin_amdgcn_mfma_f32_16x16x32_bf16(         \
                    afr[mi][kk], bfr[n][kk], acc[mi][n], 0, 0, 0);            \
    __builtin_amdgcn_s_setprio(0);                                            \
    bar();                                                                    \
    _Pragma("unroll") for (int mi = 0; mi < 2; ++mi)                          \
        _Pragma("unroll") for (int kk = 0; kk < 2; ++kk)                      \
            afr[mi][kk] = ldsfrag(AsB[cur], wr * 64 + (2 + mi) * 16 + lid, kk, lgrp); \
    if (kt + 2 < NT) {                                                        \
      stageBh(Bt, BsB[cur], 0, (kt + 2) * 64, tid);                           \
      stageBh(Bt, BsB[cur], 1, (kt + 2) * 64, tid);                           \
    }                                                                         \
    bar();                                                                    \
    __builtin_amdgcn_s_setprio(1);                                            \
    _Pragma("unroll") for (int mi = 0; mi < 2; ++mi)                          \
        _Pragma("unroll") for (int n = 0; n < 4; ++n)                         \
            _Pragma("unroll") for (int kk = 0; kk < 2; ++kk)                  \
                acc[2 + mi][n] = __builtin_amdgcn_mfma_f32_16x16x32_bf16(     \
                    afr[mi][kk], bfr[n][kk], acc[2 + mi][n], 0, 0, 0);        \
    __builtin_amdgcn_s_setprio(0);                                            \
    if (kt < NT - 2) waitvm<4>();                                             \
    else if (kt == NT - 2) waitvm<0>();                                       \
    bar();                                                                    \
    cur ^= 1;                                                                 \
  }

// QKV projection with FUSED fp32->bf16 cast on the A path.
// Grid 768 = 3 projs x 64 m x 4 n = 3 exact rounds. LDS: A f32 64KB + B 64KB.
// vmcnt math unchanged: tile-end in-flight = B(kt+1)4 + A(kt+1)4 + B(kt+2)4;
// waitvm<4> keeps only B(kt+2).
__global__ __launch_bounds__(512, 1) void k_gemm_qkv(const float* __restrict__ qF,
                                                     const float* __restrict__ kF,
                                                     const float* __restrict__ vF,
                                                     const bf16* __restrict__ Wt,
                                                     bf16* __restrict__ Qh,
                                                     bf16* __restrict__ Kh,
                                                     bf16* __restrict__ Vt) {
  __shared__ __align__(16) float AsF[2][128][64];
  __shared__ __align__(16) bf16 BsB[2][256][64];
  const int tid = threadIdx.x, lane = tid & 63, w = tid >> 6;
  const int lgrp = lane >> 4, lid = lane & 15;
  const int wr = w >> 2, wn = w & 3;
  const int bid0 = blockIdx.x;
  const int bid = (bid0 & 7) * 96 + (bid0 >> 3);  // bijective XCD swizzle
  const int proj = bid >> 8;
  const int local = bid & 255;
  const int mt = local >> 2, ntl = local & 3;
  const int m0 = mt * 128, n0 = ntl * 256;
  const float* A = proj == 0 ? qF : proj == 1 ? kF : vF;
  const float* Am = A + (size_t)m0 * 1024;
  const bf16* Bt = Wt + ((size_t)proj * 1024 + n0) * 1024;

  f32x4 acc[4][4] = {};
  constexpr int NT = 16;

  // prologue: A(0) f32 [4 loads], B(0) [4], B(1) [4]; drain 8 oldest
  stageAf(Am, AsF[0], 0, tid);
  stageBh(Bt, BsB[0], 0, 0, tid);
  stageBh(Bt, BsB[0], 1, 0, tid);
  stageBh(Bt, BsB[1], 0, 64, tid);
  stageBh(Bt, BsB[1], 1, 64, tid);
  waitvm<4>();
  bar();

  int cur = 0;
  for (int kt = 0; kt < NT; ++kt) {
    bf16x8 bfr[4][2], afr[2][2];
    // ---- phase 0 ----
#pragma unroll
    for (int n = 0; n < 4; ++n)
#pragma unroll
      for (int kk = 0; kk < 2; ++kk)
        bfr[n][kk] = ldsfrag(BsB[cur], wn * 64 + n * 16 + lid, kk, lgrp);
#pragma unroll
    for (int mi = 0; mi < 2; ++mi)
#pragma unroll
      for (int kk = 0; kk < 2; ++kk)
        afr[mi][kk] = ldsfragAf(AsF[cur], wr * 64 + mi * 16 + lid, kk, lgrp);
    if (kt + 1 < NT) stageAf(Am, AsF[cur ^ 1], (kt + 1) * 64, tid);
    bar();
    __builtin_amdgcn_s_setprio(1);
#pragma unroll
    for (int mi = 0; mi < 2; ++mi)
#pragma unroll
      for (int n = 0; n < 4; ++n)
#pragma unroll
        for (int kk = 0; kk < 2; ++kk)
          acc[mi][n] = __builtin_amdgcn_mfma_f32_16x16x32_bf16(
              afr[mi][kk], bfr[n][kk], acc[mi][n], 0, 0, 0);
    __builtin_amdgcn_s_setprio(0);
    bar();
    // ---- phase 1 ----
#pragma unroll
    for (int mi = 0; mi < 2; ++mi)
#pragma unroll
      for (int kk = 0; kk < 2; ++kk)
        afr[mi][kk] = ldsfragAf(AsF[cur], wr * 64 + (2 + mi) * 16 + lid, kk, lgrp);
    if (kt + 2 < NT) {
      stageBh(Bt, BsB[cur], 0, (kt + 2) * 64, tid);
      stageBh(Bt, BsB[cur], 1, (kt + 2) * 64, tid);
    }
    bar();
    __builtin_amdgcn_s_setprio(1);
#pragma unroll
    for (int mi = 0; mi < 2; ++mi)
#pragma unroll
      for (int n = 0; n < 4; ++n)
#pragma unroll
        for (int kk = 0; kk < 2; ++kk)
          acc[2 + mi][n] = __builtin_amdgcn_mfma_f32_16x16x32_bf16(
              afr[mi][kk], bfr[n][kk], acc[2 + mi][n], 0, 0, 0);
    __builtin_amdgcn_s_setprio(0);
    if (kt < NT - 2) waitvm<4>();        // drains A(kt+1)+B(kt+1); B(kt+2) flies
    else if (kt == NT - 2) waitvm<0>();  // final drain
    bar();
    cur ^= 1;
  }

  // epilogue (identical to R11)
  const int hh = (n0 >> 6) + wn;
  if (proj == 0) {  // Q plain [B,H,S,64]
#pragma unroll
    for (int mm = 0; mm < 4; ++mm) {
      const int rowb = m0 + wr * 64 + mm * 16 + lgrp * 4;
      const int bb = rowb >> 11, s = rowb & 2047;
#pragma unroll
      for (int n = 0; n < 4; ++n) {
        const int e = n * 16 + lid;
        bf16* dst = Qh + (((size_t)bb * 16 + hh) * 2048 + s) * 64 + e;
#pragma unroll
        for (int r = 0; r < 4; ++r) dst[(size_t)r * 64] = (bf16)acc[mm][n][r];
      }
    }
  } else if (proj == 1) {  // K row-swizzled [B,H,S,64]
#pragma unroll
    for (int mm = 0; mm < 4; ++mm) {
      const int rowb = m0 + wr * 64 + mm * 16 + lgrp * 4;
      const int bb = rowb >> 11, s = rowb & 2047;
#pragma unroll
      for (int n = 0; n < 4; ++n) {
        const int e = n * 16 + lid;
#pragma unroll
        for (int r = 0; r < 4; ++r) {
          const int sr = s + r;
          Kh[(((size_t)bb * 16 + hh) * 2048 + sr) * 64 + (e ^ ((sr & 7) << 3))] =
              (bf16)acc[mm][n][r];
        }
      }
    }
  } else {  // V^T row-swizzled [B,H,64,S]
#pragma unroll
    for (int mm = 0; mm < 4; ++mm) {
      const int rowb = m0 + wr * 64 + mm * 16 + lgrp * 4;
      const int bb = rowb >> 11, s = rowb & 2047;
#pragma unroll
      for (int n = 0; n < 4; ++n) {
        const int e = n * 16 + lid;
        union { bf16 hv[4]; uint2 u; } tmp;
#pragma unroll
        for (int r = 0; r < 4; ++r) tmp.hv[r] = (bf16)acc[mm][n][r];
        bf16* dst = Vt + (((size_t)bb * 16 + hh) * 64 + e) * 2048 + (s ^ ((e & 7) << 3));
        *reinterpret_cast<uint2*>(dst) = tmp.u;
      }
    }
  }
}

// Output projection: bf16 A, same verified schedule, grid 256 = 1 exact round.
__global__ __launch_bounds__(512, 2) void k_gemm_out8(const bf16* __restrict__ A,
                                                      const bf16* __restrict__ Wo,
                                                      float* __restrict__ C) {
  __shared__ __align__(16) bf16 AsB[2][128][64];
  __shared__ __align__(16) bf16 BsB[2][256][64];
  const int tid = threadIdx.x, lane = tid & 63, w = tid >> 6;
  const int lgrp = lane >> 4, lid = lane & 15;
  const int wr = w >> 2, wn = w & 3;
  const int bid0 = blockIdx.x;
  const int bid = (bid0 & 7) * 32 + (bid0 >> 3);  // bijective XCD swizzle (256=8*32)
  const int mt = bid >> 2, ntl = bid & 3;
  const int m0 = mt * 128, n0 = ntl * 256;
  const bf16* Am = A + (size_t)m0 * 1024;
  const bf16* Bt = Wo + (size_t)n0 * 1024;

  f32x4 acc[4][4] = {};
  constexpr int NT = 16;
  GEMM_KLOOP(Am, Bt, acc)

#pragma unroll
  for (int mm = 0; mm < 4; ++mm) {
    const int rowb = m0 + wr * 64 + mm * 16 + lgrp * 4;
#pragma unroll
    for (int n = 0; n < 4; ++n) {
      const int col = n0 + wn * 64 + n * 16 + lid;
#pragma unroll
      for (int r = 0; r < 4; ++r)
        C[(size_t)(rowb + r) * 1024 + col] = acc[mm][n][r];
    }
  }
}

// ---------------- flash attention (R11-verified, unchanged) ----------------
__global__ __launch_bounds__(256, 3) void k_flash(const bf16* __restrict__ Qh,
                                                  const bf16* __restrict__ Ksw,
                                                  const bf16* __restrict__ Vsw,
                                                  const int* __restrict__ valid,
                                                  bf16* __restrict__ Ob) {
  __shared__ __align__(16) char Ks[2][8192];
  __shared__ __align__(16) char Vs[2][8192];
  __shared__ __align__(16) char Plds[4][4096];  // per wave: 2KB per group
  const int tid = threadIdx.x, lane = tid & 63, w = tid >> 6;
  const int lgrp = lane >> 4, lid = lane & 15;
  const int blk = blockIdx.x;
  const int qt = blk & 15, bh = blk >> 4;  // consecutive blocks share (b,h)
  const int b = bh >> 4, h = bh & 15;
  const int s0 = qt * 128 + w * 32;  // wave's 32 q rows
  const bf16* Qp = Qh + ((size_t)bh * 2048 + s0) * 64;
  const bf16* Kp = Ksw + (size_t)bh * 2048 * 64;
  const bf16* Vp = Vsw + (size_t)bh * 64 * 2048;
  const int vl = valid[b];
  const int nt = (vl + 63) >> 6;
  const int full = vl >> 6;

  const int sr0 = 16 * w + (lane >> 3), col8 = (lane & 7) * 8;

  gload_lds16(Kp + (size_t)sr0 * 64 + col8, &Ks[0][(16 * w) * 128]);
  gload_lds16(Kp + (size_t)(sr0 + 8) * 64 + col8, &Ks[0][(16 * w + 8) * 128]);
  gload_lds16(Vp + (size_t)sr0 * 2048 + col8, &Vs[0][(16 * w) * 128]);
  gload_lds16(Vp + (size_t)(sr0 + 8) * 2048 + col8, &Vs[0][(16 * w + 8) * 128]);

  bf16x8 aq[2][2];
#pragma unroll
  for (int g = 0; g < 2; ++g)
#pragma unroll
    for (int c = 0; c < 2; ++c)
      aq[g][c] = *reinterpret_cast<const bf16x8*>(Qp + (g * 16 + lid) * 64 + c * 32 + lgrp * 8);

  f32x4 Of[2][4] = {};
  float mrow[2] = {-1e30f, -1e30f};
  float lpart[2] = {0.f, 0.f};
  char* Pw = &Plds[w][0];
  float* PwF = (float*)Pw;
  const int pswz = (lid & 7) << 4;

  int cur = 0;
  for (int t = 0; t < nt; ++t) {
    const int t0 = t * 64;
    __syncthreads();
    if (t + 1 < nt) {
      const int t1 = t0 + 64;
      gload_lds16(Kp + (size_t)(t1 + sr0) * 64 + col8, &Ks[cur ^ 1][(16 * w) * 128]);
      gload_lds16(Kp + (size_t)(t1 + sr0 + 8) * 64 + col8, &Ks[cur ^ 1][(16 * w + 8) * 128]);
      gload_lds16(Vp + (size_t)sr0 * 2048 + t1 + col8, &Vs[cur ^ 1][(16 * w) * 128]);
      gload_lds16(Vp + (size_t)(sr0 + 8) * 2048 + t1 + col8, &Vs[cur ^ 1][(16 * w + 8) * 128]);
    }
    f32x4 sc[2][4] = {{}, {}};
#pragma unroll
    for (int kk = 0; kk < 2; ++kk) {
      bf16x8 bkh[4];
#pragma unroll
      for (int ct = 0; ct < 4; ++ct) {
        const int row = ct * 16 + lid;
        bkh[ct] = *reinterpret_cast<const bf16x8*>(
            &Ks[cur][row * 128] + ((kk * 64 + lgrp * 16) ^ ((row & 7) << 4)));
      }
#pragma unroll
      for (int g = 0; g < 2; ++g)
#pragma unroll
        for (int ct = 0; ct < 4; ++ct)
          sc[g][ct] = __builtin_amdgcn_mfma_f32_16x16x32_bf16(bkh[ct], aq[g][kk],
                                                              sc[g][ct], 0, 0, 0);
    }
    if (t >= full) {
#pragma unroll
      for (int ct = 0; ct < 4; ++ct)
#pragma unroll
        for (int r = 0; r < 4; ++r) {
          const bool m = (t0 + ct * 16 + lgrp * 4 + r) >= vl;
          sc[0][ct][r] = m ? -1e30f : sc[0][ct][r];
          sc[1][ct][r] = m ? -1e30f : sc[1][ct][r];
        }
    }
    float vm[2];
#pragma unroll
    for (int g = 0; g < 2; ++g) {
      float v = fmaxf(fmaxf(fmaxf(sc[g][0][0], sc[g][0][1]), fmaxf(sc[g][0][2], sc[g][0][3])),
                      fmaxf(fmaxf(sc[g][1][0], sc[g][1][1]), fmaxf(sc[g][1][2], sc[g][1][3])));
      v = fmaxf(v, fmaxf(fmaxf(fmaxf(sc[g][2][0], sc[g][2][1]), fmaxf(sc[g][2][2], sc[g][2][3])),
                         fmaxf(fmaxf(sc[g][3][0], sc[g][3][1]), fmaxf(sc[g][3][2], sc[g][3][3]))));
      vm[g] = v;
    }
    if (__any((vm[0] > mrow[0] + 8.f) | (vm[1] > mrow[1] + 8.f))) {
#pragma unroll
      for (int g = 0; g < 2; ++g) {
        float v = vm[g];
        v = fmaxf(v, __shfl_xor(v, 16));
        v = fmaxf(v, __shfl_xor(v, 32));
        float mnew = fmaxf(mrow[g], v);
        float scl = fexp2(mrow[g] - mnew);
        mrow[g] = mnew;
        lpart[g] *= scl;
        if (lgrp == 0) PwF[g * 512 + lid] = scl;
      }
      asm volatile("s_waitcnt lgkmcnt(0)" ::: "memory");
      f32x4 sq0 = *reinterpret_cast<const f32x4*>(PwF + lgrp * 4);
      f32x4 sq1 = *reinterpret_cast<const f32x4*>(PwF + 512 + lgrp * 4);
#pragma unroll
      for (int f = 0; f < 4; ++f)
#pragma unroll
        for (int r = 0; r < 4; ++r) {
          Of[0][f][r] *= sq0[r];
          Of[1][f][r] *= sq1[r];
        }
    }
#pragma unroll
    for (int g = 0; g < 2; ++g)
#pragma unroll
      for (int ct = 0; ct < 4; ++ct)
#pragma unroll
        for (int r = 0; r < 4; ++r)
          sc[g][ct][r] = fexp2(sc[g][ct][r] - mrow[g]);
#pragma unroll
    for (int g = 0; g < 2; ++g)
#pragma unroll
      for (int ct = 0; ct < 4; ++ct) {
        union { bf16 hv[2]; unsigned int u; } p0, p1;
        p0.hv[0] = (bf16)sc[g][ct][0]; p0.hv[1] = (bf16)sc[g][ct][1];
        p1.hv[0] = (bf16)sc[g][ct][2]; p1.hv[1] = (bf16)sc[g][ct][3];
        char* base = Pw + g * 2048 + lid * 128 + ((ct * 32 + lgrp * 8) ^ pswz);
        *reinterpret_cast<unsigned int*>(base) = p0.u;
        *reinterpret_cast<unsigned int*>(base + 4) = p1.u;
      }
    asm volatile("s_waitcnt lgkmcnt(0)" ::: "memory");
    bf16x8 pa[2][2];
#pragma unroll
    for (int g = 0; g < 2; ++g) {
      pa[g][0] = *reinterpret_cast<const bf16x8*>(Pw + g * 2048 + lid * 128 + ((lgrp * 16) ^ pswz));
      pa[g][1] = *reinterpret_cast<const bf16x8*>(Pw + g * 2048 + lid * 128 + ((64 + lgrp * 16) ^ pswz));
    }
#pragma unroll
    for (int f = 0; f < 4; ++f) {
      const int row = f * 16 + lid;
      const char* vb = &Vs[cur][row * 128];
      const int msk = (row & 7) << 4;
      bf16x8 bv0 = *reinterpret_cast<const bf16x8*>(vb + ((lgrp * 16) ^ msk));
      bf16x8 bv1 = *reinterpret_cast<const bf16x8*>(vb + ((64 + lgrp * 16) ^ msk));
      Of[0][f] = __builtin_amdgcn_mfma_f32_16x16x32_bf16(pa[0][0], bv0, Of[0][f], 0, 0, 0);
      Of[0][f] = __builtin_amdgcn_mfma_f32_16x16x32_bf16(pa[0][1], bv1, Of[0][f], 0, 0, 0);
      Of[1][f] = __builtin_amdgcn_mfma_f32_16x16x32_bf16(pa[1][0], bv0, Of[1][f], 0, 0, 0);
      Of[1][f] = __builtin_amdgcn_mfma_f32_16x16x32_bf16(pa[1][1], bv1, Of[1][f], 0, 0, 0);
    }
#pragma unroll
    for (int g = 0; g < 2; ++g)
      lpart[g] += ((sc[g][0][0] + sc[g][0][1]) + (sc[g][0][2] + sc[g][0][3])) +
                  ((sc[g][1][0] + sc[g][1][1]) + (sc[g][1][2] + sc[g][1][3])) +
                  ((sc[g][2][0] + sc[g][2][1]) + (sc[g][2][2] + sc[g][2][3])) +
                  ((sc[g][3][0] + sc[g][3][1]) + (sc[g][3][2] + sc[g][3][3]));
    cur ^= 1;
  }
#pragma unroll
  for (int g = 0; g < 2; ++g) {
    float l = lpart[g];
    l += __shfl_xor(l, 16);
    l += __shfl_xor(l, 32);
    if (lgrp == 0) PwF[g * 512 + lid] = 1.f / l;
  }
  asm volatile("s_waitcnt lgkmcnt(0)" ::: "memory");
  f32x4 iq0 = *reinterpret_cast<const f32x4*>(PwF + lgrp * 4);
  f32x4 iq1 = *reinterpret_cast<const f32x4*>(PwF + 512 + lgrp * 4);
  bf16* Op = Ob + ((size_t)b * 2048 + s0) * 1024 + h * 64;
#pragma unroll
  for (int r = 0; r < 4; ++r)
#pragma unroll
    for (int f = 0; f < 4; ++f) {
      Op[(size_t)(lgrp * 4 + r) * 1024 + f * 16 + lid] = (bf16)(Of[0][f][r] * iq0[r]);
      Op[(size_t)(16 + lgrp * 4 + r) * 1024 + f * 16 + lid] = (bf16)(Of[1][f][r] * iq1[r]);
    }
}

// ---------------- launch ----------------
extern "C" void kernel_launch(void* const* d_in, const int* in_sizes, int n_in,
                              void* d_out, int out_size, void* d_ws, size_t ws_size,
                              hipStream_t stream) {
  const float* q = (const float*)d_in[0];
  const float* k = (const float*)d_in[1];
  const float* v = (const float*)d_in[2];
  const int* vl = (const int*)d_in[3];
  const float* Wq = (const float*)d_in[4];
  const float* Wk = (const float*)d_in[5];
  const float* Wv = (const float*)d_in[6];
  const float* Wo = (const float*)d_in[7];

  char* ws = (char*)d_ws;
  const size_t SZW = (size_t)1024 * 1024 * 2;  // 2MB per weight matrix
  const size_t SZT = (size_t)8192 * 1024 * 2;  // 16MB per bf16 activation tensor
  bf16* WqkvT = (bf16*)(ws);                   // 6MB [3072][1024]
  bf16* WoT = (bf16*)(ws + 3 * SZW);
  bf16* Qh  = (bf16*)(ws + 4 * SZW);
  bf16* Kh  = (bf16*)(ws + 4 * SZW + SZT);
  bf16* Vt  = (bf16*)(ws + 4 * SZW + 2 * SZT);
  bf16* attnb = (bf16*)(ws + 4 * SZW + 3 * SZT);

  k_cvt_w<<<16384, 256, 0, stream>>>(Wq, Wk, Wv, Wo, WqkvT, WoT);
  k_gemm_qkv<<<768, 512, 0, stream>>>(q, k, v, WqkvT, Qh, Kh, Vt);
  k_flash<<<1024, 256, 0, stream>>>(Qh, Kh, Vt, vl, attnb);
  k_gemm_out8<<<256, 512, 0, stream>>>(attnb, WoT, (float*)d_out);
}

// Round 13
// 177.674 us; speedup vs baseline: 1.0519x; 1.0519x over previous
//
#include <hip/hip_runtime.h>
#include <hip/hip_bf16.h>

typedef __bf16 bf16;
typedef __attribute__((ext_vector_type(8))) __bf16 bf16x8;
typedef __attribute__((ext_vector_type(4))) float f32x4;

#define DEV __device__ __forceinline__

DEV float fexp2(float x) {
#if __has_builtin(__builtin_amdgcn_exp2f)
  return __builtin_amdgcn_exp2f(x);
#else
  return exp2f(x);
#endif
}

// async global->LDS, 16B per lane; LDS dest = wave-uniform base + lane*16
DEV void gload_lds16(const void* g, void* l) {
  __builtin_amdgcn_global_load_lds(
      (__attribute__((address_space(1))) void*)(g),
      (__attribute__((address_space(3))) void*)(l), 16, 0, 0);
}

template <int N>
DEV void waitvm() { asm volatile("s_waitcnt vmcnt(%0)" ::"n"(N) : "memory"); }
DEV void fence() { asm volatile("" ::: "memory"); }
DEV void bar() { fence(); __builtin_amdgcn_s_barrier(); fence(); }

// ---------------- fused conversion kernel (acts + weights, one launch) -------
// blocks [0,12288): q/k/v fp32 -> bf16 (8 elems/thread)
// blocks [12288,28672): Wq/Wk/Wv -> WqkvT [3072][1024] (Wq pre-scaled into
// exp2 domain); Wo -> WoT transposed.
__global__ void k_cvt_all(const float* __restrict__ q, const float* __restrict__ k,
                          const float* __restrict__ v, const float* __restrict__ Wq,
                          const float* __restrict__ Wk, const float* __restrict__ Wv,
                          const float* __restrict__ Wo, bf16* __restrict__ qb,
                          bf16* __restrict__ kb, bf16* __restrict__ vb,
                          bf16* __restrict__ WqkvT, bf16* __restrict__ WoT) {
  const int bid = blockIdx.x;
  if (bid < 12288) {
    const int which = bid >> 12;  // 4096 blocks per tensor
    const float* in = which == 0 ? q : which == 1 ? k : v;
    bf16* out = which == 0 ? qb : which == 1 ? kb : vb;
    const int i = (bid & 4095) * 256 + threadIdx.x;
    const float4* p = reinterpret_cast<const float4*>(in) + (size_t)i * 2;
    float4 a = p[0], b = p[1];
    bf16x8 o;
    o[0] = (bf16)a.x; o[1] = (bf16)a.y; o[2] = (bf16)a.z; o[3] = (bf16)a.w;
    o[4] = (bf16)b.x; o[5] = (bf16)b.y; o[6] = (bf16)b.z; o[7] = (bf16)b.w;
    *reinterpret_cast<bf16x8*>(out + (size_t)i * 8) = o;
  } else {
    const int idx = (bid - 12288) * 256 + threadIdx.x;  // 0..4M
    const int which = idx >> 20, r = idx & ((1 << 20) - 1);
    if (which < 3) {
      const float* W = which == 0 ? Wq : which == 1 ? Wk : Wv;
      const int d = r & 1023, n = r >> 10;
      float val = W[((size_t)(n >> 6) << 16) + (size_t)d * 64 + (n & 63)];
      if (which == 0) val *= 0.180336880f;  // 1/sqrt(64) * log2(e)
      WqkvT[((size_t)which << 20) + r] = (bf16)val;
    } else {
      const int kk = r & 1023, n = r >> 10;
      WoT[r] = (bf16)Wo[(size_t)kk * 1024 + n];
    }
  }
}

// ---------------- 8-phase 128x256 GEMM building blocks (R8-verified) --------
DEV void stageA(const bf16* __restrict__ Am, bf16 (*lds)[64], int k0, int tid) {
  const int wv = tid >> 6;
#pragma unroll
  for (int l = 0; l < 2; ++l) {
    const int row = l * 64 + (tid >> 3);
    const int e = (((tid & 7) ^ (row & 7)) << 3);
    gload_lds16(Am + (size_t)row * 1024 + k0 + e,
                (char*)lds + l * 8192 + wv * 1024);
  }
}
DEV void stageBh(const bf16* __restrict__ Bt, bf16 (*lds)[64], int h, int k0, int tid) {
  const int wv = tid >> 6;
#pragma unroll
  for (int l = 0; l < 2; ++l) {
    const int row = h * 128 + l * 64 + (tid >> 3);
    const int e = (((tid & 7) ^ (row & 7)) << 3);
    gload_lds16(Bt + (size_t)row * 1024 + k0 + e,
                (char*)lds + h * 16384 + l * 8192 + wv * 1024);
  }
}
DEV bf16x8 ldsfrag(const bf16 (*lds)[64], int row, int kk, int lgrp) {
  const int ch = ((kk << 2) + lgrp) ^ (row & 7);
  return *reinterpret_cast<const bf16x8*>((const char*)&lds[row][0] + (ch << 4));
}

// K-loop macro shared by qkv and out GEMMs (R7/R8-verified schedule)
#define GEMM_KLOOP(Am, Bt, acc)                                               \
  stageA(Am, AsB[0], 0, tid);                                                 \
  stageBh(Bt, BsB[0], 0, 0, tid);                                             \
  stageBh(Bt, BsB[0], 1, 0, tid);                                             \
  stageBh(Bt, BsB[1], 0, 64, tid);                                            \
  stageBh(Bt, BsB[1], 1, 64, tid);                                            \
  waitvm<4>();                                                                \
  bar();                                                                      \
  int cur = 0;                                                                \
  for (int kt = 0; kt < NT; ++kt) {                                           \
    bf16x8 bfr[4][2], afr[2][2];                                              \
    _Pragma("unroll") for (int n = 0; n < 4; ++n)                             \
        _Pragma("unroll") for (int kk = 0; kk < 2; ++kk)                      \
            bfr[n][kk] = ldsfrag(BsB[cur], wn * 64 + n * 16 + lid, kk, lgrp); \
    _Pragma("unroll") for (int mi = 0; mi < 2; ++mi)                          \
        _Pragma("unroll") for (int kk = 0; kk < 2; ++kk)                      \
            afr[mi][kk] = ldsfrag(AsB[cur], wr * 64 + mi * 16 + lid, kk, lgrp); \
    if (kt + 1 < NT) stageA(Am, AsB[cur ^ 1], (kt + 1) * 64, tid);            \
    bar();                                                                    \
    __builtin_amdgcn_s_setprio(1);                                            \
    _Pragma("unroll") for (int mi = 0; mi < 2; ++mi)                          \
        _Pragma("unroll") for (int n = 0; n < 4; ++n)                         \
            _Pragma("unroll") for (int kk = 0; kk < 2; ++kk)                  \
                acc[mi][n] = __builtin_amdgcn_mfma_f32_16x16x32_bf16(         \
                    afr[mi][kk], bfr[n][kk], acc[mi][n], 0, 0, 0);            \
    __builtin_amdgcn_s_setprio(0);                                            \
    bar();                                                                    \
    _Pragma("unroll") for (int mi = 0; mi < 2; ++mi)                          \
        _Pragma("unroll") for (int kk = 0; kk < 2; ++kk)                      \
            afr[mi][kk] = ldsfrag(AsB[cur], wr * 64 + (2 + mi) * 16 + lid, kk, lgrp); \
    if (kt + 2 < NT) {                                                        \
      stageBh(Bt, BsB[cur], 0, (kt + 2) * 64, tid);                           \
      stageBh(Bt, BsB[cur], 1, (kt + 2) * 64, tid);                           \
    }                                                                         \
    bar();                                                                    \
    __builtin_amdgcn_s_setprio(1);                                            \
    _Pragma("unroll") for (int mi = 0; mi < 2; ++mi)                          \
        _Pragma("unroll") for (int n = 0; n < 4; ++n)                         \
            _Pragma("unroll") for (int kk = 0; kk < 2; ++kk)                  \
                acc[2 + mi][n] = __builtin_amdgcn_mfma_f32_16x16x32_bf16(     \
                    afr[mi][kk], bfr[n][kk], acc[2 + mi][n], 0, 0, 0);        \
    __builtin_amdgcn_s_setprio(0);                                            \
    if (kt < NT - 2) waitvm<4>();                                             \
    else if (kt == NT - 2) waitvm<0>();                                       \
    bar();                                                                    \
    cur ^= 1;                                                                 \
  }

// QKV projection: grid 768 = 3 projs x 64 m x 4 n = 3 exact rounds.
__global__ __launch_bounds__(512, 2) void k_gemm_qkv(const bf16* __restrict__ qA,
                                                     const bf16* __restrict__ kA,
                                                     const bf16* __restrict__ vA,
                                                     const bf16* __restrict__ Wt,
                                                     bf16* __restrict__ Qh,
                                                     bf16* __restrict__ Kh,
                                                     bf16* __restrict__ Vt) {
  __shared__ __align__(16) bf16 AsB[2][128][64];
  __shared__ __align__(16) bf16 BsB[2][256][64];
  const int tid = threadIdx.x, lane = tid & 63, w = tid >> 6;
  const int lgrp = lane >> 4, lid = lane & 15;
  const int wr = w >> 2, wn = w & 3;
  const int bid0 = blockIdx.x;
  const int bid = (bid0 & 7) * 96 + (bid0 >> 3);  // bijective XCD swizzle
  const int proj = bid >> 8;
  const int local = bid & 255;
  const int mt = local >> 2, ntl = local & 3;
  const int m0 = mt * 128, n0 = ntl * 256;
  const bf16* A = proj == 0 ? qA : proj == 1 ? kA : vA;
  const bf16* Am = A + (size_t)m0 * 1024;
  const bf16* Bt = Wt + ((size_t)proj * 1024 + n0) * 1024;

  f32x4 acc[4][4] = {};
  constexpr int NT = 16;
  GEMM_KLOOP(Am, Bt, acc)

  const int hh = (n0 >> 6) + wn;
  if (proj == 0) {  // Q plain [B,H,S,64]
#pragma unroll
    for (int mm = 0; mm < 4; ++mm) {
      const int rowb = m0 + wr * 64 + mm * 16 + lgrp * 4;
      const int bb = rowb >> 11, s = rowb & 2047;
#pragma unroll
      for (int n = 0; n < 4; ++n) {
        const int e = n * 16 + lid;
        bf16* dst = Qh + (((size_t)bb * 16 + hh) * 2048 + s) * 64 + e;
#pragma unroll
        for (int r = 0; r < 4; ++r) dst[(size_t)r * 64] = (bf16)acc[mm][n][r];
      }
    }
  } else if (proj == 1) {  // K row-swizzled [B,H,S,64]
#pragma unroll
    for (int mm = 0; mm < 4; ++mm) {
      const int rowb = m0 + wr * 64 + mm * 16 + lgrp * 4;
      const int bb = rowb >> 11, s = rowb & 2047;
#pragma unroll
      for (int n = 0; n < 4; ++n) {
        const int e = n * 16 + lid;
#pragma unroll
        for (int r = 0; r < 4; ++r) {
          const int sr = s + r;
          Kh[(((size_t)bb * 16 + hh) * 2048 + sr) * 64 + (e ^ ((sr & 7) << 3))] =
              (bf16)acc[mm][n][r];
        }
      }
    }
  } else {  // V^T row-swizzled [B,H,64,S]
#pragma unroll
    for (int mm = 0; mm < 4; ++mm) {
      const int rowb = m0 + wr * 64 + mm * 16 + lgrp * 4;
      const int bb = rowb >> 11, s = rowb & 2047;
#pragma unroll
      for (int n = 0; n < 4; ++n) {
        const int e = n * 16 + lid;
        union { bf16 hv[4]; uint2 u; } tmp;
#pragma unroll
        for (int r = 0; r < 4; ++r) tmp.hv[r] = (bf16)acc[mm][n][r];
        bf16* dst = Vt + (((size_t)bb * 16 + hh) * 64 + e) * 2048 + (s ^ ((e & 7) << 3));
        *reinterpret_cast<uint2*>(dst) = tmp.u;
      }
    }
  }
}

// Output projection: same 8-phase loop, grid 256 = 1 exact round.
__global__ __launch_bounds__(512, 2) void k_gemm_out8(const bf16* __restrict__ A,
                                                      const bf16* __restrict__ Wo,
                                                      float* __restrict__ C) {
  __shared__ __align__(16) bf16 AsB[2][128][64];
  __shared__ __align__(16) bf16 BsB[2][256][64];
  const int tid = threadIdx.x, lane = tid & 63, w = tid >> 6;
  const int lgrp = lane >> 4, lid = lane & 15;
  const int wr = w >> 2, wn = w & 3;
  const int bid0 = blockIdx.x;
  const int bid = (bid0 & 7) * 32 + (bid0 >> 3);  // bijective XCD swizzle (256=8*32)
  const int mt = bid >> 2, ntl = bid & 3;
  const int m0 = mt * 128, n0 = ntl * 256;
  const bf16* Am = A + (size_t)m0 * 1024;
  const bf16* Bt = Wo + (size_t)n0 * 1024;

  f32x4 acc[4][4] = {};
  constexpr int NT = 16;
  GEMM_KLOOP(Am, Bt, acc)

#pragma unroll
  for (int mm = 0; mm < 4; ++mm) {
    const int rowb = m0 + wr * 64 + mm * 16 + lgrp * 4;
#pragma unroll
    for (int n = 0; n < 4; ++n) {
      const int col = n0 + wn * 64 + n * 16 + lid;
#pragma unroll
      for (int r = 0; r < 4; ++r)
        C[(size_t)(rowb + r) * 1024 + col] = acc[mm][n][r];
    }
  }
}

// ---------------- flash attention: 4 waves x 32 q (two 16-q groups) ----------
// Plain blockIdx: consecutive blocks share (b,h) for L2 reuse; round-robin
// dispatch balances per-CU work (R10 lesson: XCD-grouping by head -> 2x slower).
__global__ __launch_bounds__(256, 3) void k_flash(const bf16* __restrict__ Qh,
                                                  const bf16* __restrict__ Ksw,
                                                  const bf16* __restrict__ Vsw,
                                                  const int* __restrict__ valid,
                                                  bf16* __restrict__ Ob) {
  __shared__ __align__(16) char Ks[2][8192];
  __shared__ __align__(16) char Vs[2][8192];
  __shared__ __align__(16) char Plds[4][4096];  // per wave: 2KB per group
  const int tid = threadIdx.x, lane = tid & 63, w = tid >> 6;
  const int lgrp = lane >> 4, lid = lane & 15;
  const int blk = blockIdx.x;
  const int qt = blk & 15, bh = blk >> 4;  // consecutive blocks share (b,h)
  const int b = bh >> 4, h = bh & 15;
  const int s0 = qt * 128 + w * 32;  // wave's 32 q rows
  const bf16* Qp = Qh + ((size_t)bh * 2048 + s0) * 64;
  const bf16* Kp = Ksw + (size_t)bh * 2048 * 64;
  const bf16* Vp = Vsw + (size_t)bh * 64 * 2048;
  const int vl = valid[b];
  const int nt = (vl + 63) >> 6;
  const int full = vl >> 6;

  // staging: wave w stages rows [16w,16w+16) of K and V (2 gloads each)
  const int sr0 = 16 * w + (lane >> 3), col8 = (lane & 7) * 8;

  gload_lds16(Kp + (size_t)sr0 * 64 + col8, &Ks[0][(16 * w) * 128]);
  gload_lds16(Kp + (size_t)(sr0 + 8) * 64 + col8, &Ks[0][(16 * w + 8) * 128]);
  gload_lds16(Vp + (size_t)sr0 * 2048 + col8, &Vs[0][(16 * w) * 128]);
  gload_lds16(Vp + (size_t)(sr0 + 8) * 2048 + col8, &Vs[0][(16 * w + 8) * 128]);

  // Q A-frags per group (q = s0 + g*16 + lid)
  bf16x8 aq[2][2];
#pragma unroll
  for (int g = 0; g < 2; ++g)
#pragma unroll
    for (int c = 0; c < 2; ++c)
      aq[g][c] = *reinterpret_cast<const bf16x8*>(Qp + (g * 16 + lid) * 64 + c * 32 + lgrp * 8);

  f32x4 Of[2][4] = {};
  float mrow[2] = {-1e30f, -1e30f};
  float lpart[2] = {0.f, 0.f};
  char* Pw = &Plds[w][0];
  float* PwF = (float*)Pw;
  const int pswz = (lid & 7) << 4;

  int cur = 0;
  for (int t = 0; t < nt; ++t) {
    const int t0 = t * 64;
    __syncthreads();  // buf[cur] staged & visible (vmcnt drained at barrier)
    if (t + 1 < nt) {
      const int t1 = t0 + 64;
      gload_lds16(Kp + (size_t)(t1 + sr0) * 64 + col8, &Ks[cur ^ 1][(16 * w) * 128]);
      gload_lds16(Kp + (size_t)(t1 + sr0 + 8) * 64 + col8, &Ks[cur ^ 1][(16 * w + 8) * 128]);
      gload_lds16(Vp + (size_t)sr0 * 2048 + t1 + col8, &Vs[cur ^ 1][(16 * w) * 128]);
      gload_lds16(Vp + (size_t)(sr0 + 8) * 2048 + t1 + col8, &Vs[cur ^ 1][(16 * w + 8) * 128]);
    }
    // swapped scores, two kk-halves; K frags shared by both q-groups
    f32x4 sc[2][4] = {{}, {}};
#pragma unroll
    for (int kk = 0; kk < 2; ++kk) {
      bf16x8 bkh[4];
#pragma unroll
      for (int ct = 0; ct < 4; ++ct) {
        const int row = ct * 16 + lid;
        bkh[ct] = *reinterpret_cast<const bf16x8*>(
            &Ks[cur][row * 128] + ((kk * 64 + lgrp * 16) ^ ((row & 7) << 4)));
      }
#pragma unroll
      for (int g = 0; g < 2; ++g)
#pragma unroll
        for (int ct = 0; ct < 4; ++ct)
          sc[g][ct] = __builtin_amdgcn_mfma_f32_16x16x32_bf16(bkh[ct], aq[g][kk],
                                                              sc[g][ct], 0, 0, 0);
    }
    if (t >= full) {  // key mask identical for both groups
#pragma unroll
      for (int ct = 0; ct < 4; ++ct)
#pragma unroll
        for (int r = 0; r < 4; ++r) {
          const bool m = (t0 + ct * 16 + lgrp * 4 + r) >= vl;
          sc[0][ct][r] = m ? -1e30f : sc[0][ct][r];
          sc[1][ct][r] = m ? -1e30f : sc[1][ct][r];
        }
    }
    float vm[2];
#pragma unroll
    for (int g = 0; g < 2; ++g) {
      float v = fmaxf(fmaxf(fmaxf(sc[g][0][0], sc[g][0][1]), fmaxf(sc[g][0][2], sc[g][0][3])),
                      fmaxf(fmaxf(sc[g][1][0], sc[g][1][1]), fmaxf(sc[g][1][2], sc[g][1][3])));
      v = fmaxf(v, fmaxf(fmaxf(fmaxf(sc[g][2][0], sc[g][2][1]), fmaxf(sc[g][2][2], sc[g][2][3])),
                         fmaxf(fmaxf(sc[g][3][0], sc[g][3][1]), fmaxf(sc[g][3][2], sc[g][3][3]))));
      vm[g] = v;
    }
    if (__any((vm[0] > mrow[0] + 8.f) | (vm[1] > mrow[1] + 8.f))) {  // rare
#pragma unroll
      for (int g = 0; g < 2; ++g) {
        float v = vm[g];
        v = fmaxf(v, __shfl_xor(v, 16));
        v = fmaxf(v, __shfl_xor(v, 32));
        float mnew = fmaxf(mrow[g], v);
        float scl = fexp2(mrow[g] - mnew);
        mrow[g] = mnew;
        lpart[g] *= scl;
        if (lgrp == 0) PwF[g * 512 + lid] = scl;
      }
      asm volatile("s_waitcnt lgkmcnt(0)" ::: "memory");
      f32x4 sq0 = *reinterpret_cast<const f32x4*>(PwF + lgrp * 4);
      f32x4 sq1 = *reinterpret_cast<const f32x4*>(PwF + 512 + lgrp * 4);
#pragma unroll
      for (int f = 0; f < 4; ++f)
#pragma unroll
        for (int r = 0; r < 4; ++r) {
          Of[0][f][r] *= sq0[r];
          Of[1][f][r] *= sq1[r];
        }
    }
#pragma unroll
    for (int g = 0; g < 2; ++g)
#pragma unroll
      for (int ct = 0; ct < 4; ++ct)
#pragma unroll
        for (int r = 0; r < 4; ++r)
          sc[g][ct][r] = fexp2(sc[g][ct][r] - mrow[g]);
    // P write (both groups), single lgkm wait, P reads
#pragma unroll
    for (int g = 0; g < 2; ++g)
#pragma unroll
      for (int ct = 0; ct < 4; ++ct) {
        union { bf16 hv[2]; unsigned int u; } p0, p1;
        p0.hv[0] = (bf16)sc[g][ct][0]; p0.hv[1] = (bf16)sc[g][ct][1];
        p1.hv[0] = (bf16)sc[g][ct][2]; p1.hv[1] = (bf16)sc[g][ct][3];
        char* base = Pw + g * 2048 + lid * 128 + ((ct * 32 + lgrp * 8) ^ pswz);
        *reinterpret_cast<unsigned int*>(base) = p0.u;
        *reinterpret_cast<unsigned int*>(base + 4) = p1.u;
      }
    asm volatile("s_waitcnt lgkmcnt(0)" ::: "memory");
    bf16x8 pa[2][2];
#pragma unroll
    for (int g = 0; g < 2; ++g) {
      pa[g][0] = *reinterpret_cast<const bf16x8*>(Pw + g * 2048 + lid * 128 + ((lgrp * 16) ^ pswz));
      pa[g][1] = *reinterpret_cast<const bf16x8*>(Pw + g * 2048 + lid * 128 + ((64 + lgrp * 16) ^ pswz));
    }
    // PV: V frags loaded once, used by both groups
#pragma unroll
    for (int f = 0; f < 4; ++f) {
      const int row = f * 16 + lid;
      const char* vb = &Vs[cur][row * 128];
      const int msk = (row & 7) << 4;
      bf16x8 bv0 = *reinterpret_cast<const bf16x8*>(vb + ((lgrp * 16) ^ msk));
      bf16x8 bv1 = *reinterpret_cast<const bf16x8*>(vb + ((64 + lgrp * 16) ^ msk));
      Of[0][f] = __builtin_amdgcn_mfma_f32_16x16x32_bf16(pa[0][0], bv0, Of[0][f], 0, 0, 0);
      Of[0][f] = __builtin_amdgcn_mfma_f32_16x16x32_bf16(pa[0][1], bv1, Of[0][f], 0, 0, 0);
      Of[1][f] = __builtin_amdgcn_mfma_f32_16x16x32_bf16(pa[1][0], bv0, Of[1][f], 0, 0, 0);
      Of[1][f] = __builtin_amdgcn_mfma_f32_16x16x32_bf16(pa[1][1], bv1, Of[1][f], 0, 0, 0);
    }
#pragma unroll
    for (int g = 0; g < 2; ++g)
      lpart[g] += ((sc[g][0][0] + sc[g][0][1]) + (sc[g][0][2] + sc[g][0][3])) +
                  ((sc[g][1][0] + sc[g][1][1]) + (sc[g][1][2] + sc[g][1][3])) +
                  ((sc[g][2][0] + sc[g][2][1]) + (sc[g][2][2] + sc[g][2][3])) +
                  ((sc[g][3][0] + sc[g][3][1]) + (sc[g][3][2] + sc[g][3][3]));
    cur ^= 1;
  }
  // epilogue
#pragma unroll
  for (int g = 0; g < 2; ++g) {
    float l = lpart[g];
    l += __shfl_xor(l, 16);
    l += __shfl_xor(l, 32);
    if (lgrp == 0) PwF[g * 512 + lid] = 1.f / l;
  }
  asm volatile("s_waitcnt lgkmcnt(0)" ::: "memory");
  f32x4 iq0 = *reinterpret_cast<const f32x4*>(PwF + lgrp * 4);
  f32x4 iq1 = *reinterpret_cast<const f32x4*>(PwF + 512 + lgrp * 4);
  bf16* Op = Ob + ((size_t)b * 2048 + s0) * 1024 + h * 64;
#pragma unroll
  for (int r = 0; r < 4; ++r)
#pragma unroll
    for (int f = 0; f < 4; ++f) {
      Op[(size_t)(lgrp * 4 + r) * 1024 + f * 16 + lid] = (bf16)(Of[0][f][r] * iq0[r]);
      Op[(size_t)(16 + lgrp * 4 + r) * 1024 + f * 16 + lid] = (bf16)(Of[1][f][r] * iq1[r]);
    }
}

// ---------------- launch ----------------
extern "C" void kernel_launch(void* const* d_in, const int* in_sizes, int n_in,
                              void* d_out, int out_size, void* d_ws, size_t ws_size,
                              hipStream_t stream) {
  const float* q = (const float*)d_in[0];
  const float* k = (const float*)d_in[1];
  const float* v = (const float*)d_in[2];
  const int* vl = (const int*)d_in[3];
  const float* Wq = (const float*)d_in[4];
  const float* Wk = (const float*)d_in[5];
  const float* Wv = (const float*)d_in[6];
  const float* Wo = (const float*)d_in[7];

  char* ws = (char*)d_ws;
  const size_t SZW = (size_t)1024 * 1024 * 2;  // 2MB per weight matrix
  const size_t SZT = (size_t)8192 * 1024 * 2;  // 16MB per bf16 activation tensor
  bf16* WqkvT = (bf16*)(ws);                   // 6MB [3072][1024]
  bf16* WoT = (bf16*)(ws + 3 * SZW);
  bf16* Qh  = (bf16*)(ws + 4 * SZW);
  bf16* Kh  = (bf16*)(ws + 4 * SZW + SZT);
  bf16* Vt  = (bf16*)(ws + 4 * SZW + 2 * SZT);
  bf16* qb  = (bf16*)(ws + 4 * SZW + 3 * SZT);
  bf16* kb  = (bf16*)(ws + 4 * SZW + 4 * SZT);
  bf16* vb  = (bf16*)(ws + 4 * SZW + 5 * SZT);
  bf16* attnb = qb;  // qb dead after projections

  k_cvt_all<<<28672, 256, 0, stream>>>(q, k, v, Wq, Wk, Wv, Wo, qb, kb, vb,
                                       WqkvT, WoT);
  k_gemm_qkv<<<768, 512, 0, stream>>>(qb, kb, vb, WqkvT, Qh, Kh, Vt);
  k_flash<<<1024, 256, 0, stream>>>(Qh, Kh, Vt, vl, attnb);
  k_gemm_out8<<<256, 512, 0, stream>>>(attnb, WoT, (float*)d_out);
}